// Round 3
// baseline (539.745 us; speedup 1.0000x reference)
//
#include <hip/hip_runtime.h>
#include <hip/hip_bf16.h>

#define D_MODEL 1024
#define SEQ 2048
#define NH 16
#define HSZ 64
#define DFF_ 4096

typedef __attribute__((ext_vector_type(8))) short short8;
typedef __attribute__((ext_vector_type(4))) short short4v;
typedef __attribute__((ext_vector_type(4))) float f32x4;

static __device__ __forceinline__ short f2bf(float f) {
  unsigned u = __builtin_bit_cast(unsigned, f);
  u = u + 0x7fffu + ((u >> 16) & 1u);
  return (short)(u >> 16);
}

static __device__ __forceinline__ unsigned packbf2(float a, float b) {
  return (unsigned)(unsigned short)f2bf(a) | ((unsigned)(unsigned short)f2bf(b) << 16);
}

static __device__ __forceinline__ f32x4 mfma16(short8 a, short8 b, f32x4 c) {
  return __builtin_amdgcn_mfma_f32_16x16x32_bf16(a, b, c, 0, 0, 0);
}

static __device__ __forceinline__ void gld16(const short* g, short* l) {
  __builtin_amdgcn_global_load_lds((const __attribute__((address_space(1))) void*)g,
                                   (__attribute__((address_space(3))) void*)l, 16, 0, 0);
}

// ---------------- weight transpose/convert kernels ----------------
__global__ void transpose_qkv_kernel(const float* __restrict__ Wq, const float* __restrict__ Wk,
                                     const float* __restrict__ Wv, short* __restrict__ dst) {
  __shared__ float tile[32][33];
  const int z = blockIdx.z;
  const int which = z >> 4, hh = z & 15;
  const float* src = (which == 0 ? Wq : which == 1 ? Wk : Wv) + (long)hh * (D_MODEL * HSZ);
  const int c0 = blockIdx.x * 32, r0 = blockIdx.y * 32;
  const int tx = threadIdx.x, ty = threadIdx.y;
#pragma unroll
  for (int i = 0; i < 4; ++i)
    tile[ty + 8 * i][tx] = src[(long)(r0 + ty + 8 * i) * HSZ + c0 + tx];
  __syncthreads();
#pragma unroll
  for (int i = 0; i < 4; ++i)
    dst[((long)which * 1024 + hh * 64 + c0 + ty + 8 * i) * D_MODEL + r0 + tx] =
        f2bf(tile[tx][ty + 8 * i]);
}

__global__ void transpose_gen_kernel(const float* __restrict__ src, short* __restrict__ dst,
                                     int R, int C) {
  __shared__ float tile[32][33];
  const int c0 = blockIdx.x * 32, r0 = blockIdx.y * 32;
  const int tx = threadIdx.x, ty = threadIdx.y;
#pragma unroll
  for (int i = 0; i < 4; ++i)
    tile[ty + 8 * i][tx] = src[(long)(r0 + ty + 8 * i) * C + c0 + tx];
  __syncthreads();
#pragma unroll
  for (int i = 0; i < 4; ++i)
    dst[(long)(c0 + ty + 8 * i) * R + r0 + tx] = f2bf(tile[tx][ty + 8 * i]);
}

// V: [B,H,S,HS] -> [B,H,HS,S] (bf16)
__global__ void v_transpose_kernel(const short* __restrict__ vb, short* __restrict__ vt) {
  __shared__ short tile[64 * 72];
  const int bh = blockIdx.y;
  const int t0 = blockIdx.x * 64;
  const long base = (long)bh * SEQ * HSZ;
  const int tid = threadIdx.x;
  const int r = tid >> 3, c = (tid & 7) * 8;
#pragma unroll
  for (int it = 0; it < 2; ++it) {
    const int rr = r + it * 32;
    *(short8*)&tile[rr * 72 + c] = *(const short8*)(vb + base + (long)(t0 + rr) * HSZ + c);
  }
  __syncthreads();
#pragma unroll
  for (int it = 0; it < 2; ++it) {
    const int rr = r + it * 32;  // hs row
    short8 o;
#pragma unroll
    for (int u = 0; u < 8; ++u) o[u] = tile[(c + u) * 72 + rr];
    *(short8*)(vt + base + (long)rr * SEQ + t0 + c) = o;
  }
}

// ---------------- layernorm (f32 in -> bf16 out) ----------------
__global__ void ln_kernel(const float* __restrict__ x, const float* __restrict__ w,
                          const float* __restrict__ b, short* __restrict__ out) {
  const int row = blockIdx.x;
  const float* xr = x + (size_t)row * D_MODEL;
  const int t = threadIdx.x;  // 256
  float4 v = *(const float4*)(xr + t * 4);
  float s = v.x + v.y + v.z + v.w;
  float s2 = v.x * v.x + v.y * v.y + v.z * v.z + v.w * v.w;
#pragma unroll
  for (int o = 1; o < 64; o <<= 1) {
    s += __shfl_xor(s, o, 64);
    s2 += __shfl_xor(s2, o, 64);
  }
  __shared__ float ps[8];
  const int lane = t & 63, wid = t >> 6;
  if (lane == 0) { ps[wid] = s; ps[wid + 4] = s2; }
  __syncthreads();
  s = ps[0] + ps[1] + ps[2] + ps[3];
  s2 = ps[4] + ps[5] + ps[6] + ps[7];
  const float mu = s * (1.0f / D_MODEL);
  const float var = s2 * (1.0f / D_MODEL) - mu * mu;
  const float rs = rsqrtf(var + 1e-5f);
  float4 wv = *(const float4*)(w + t * 4);
  float4 bv = *(const float4*)(b + t * 4);
  short4v o4;
  o4[0] = f2bf((v.x - mu) * rs * wv.x + bv.x);
  o4[1] = f2bf((v.y - mu) * rs * wv.y + bv.y);
  o4[2] = f2bf((v.z - mu) * rs * wv.z + bv.z);
  o4[3] = f2bf((v.w - mu) * rs * wv.w + bv.w);
  *(short4v*)(out + (size_t)row * D_MODEL + t * 4) = o4;
}

// ---------------- GEMM (m97 structure, BK=64 as two 32-K panels) ----------------
// MODE 0: qkv  MODE 1: proj(+res)  MODE 2: ffn1(+gelu)  MODE 3: ffn2(+res)
#define BM 128
#define BN 128

template <int MODE>
__global__ void gemm_kernel(const short* __restrict__ A, const short* __restrict__ Bt,
                            const int K, const float* __restrict__ c0,
                            const float* __restrict__ c1, const float* __restrict__ c2,
                            const float* __restrict__ res, void* __restrict__ o0,
                            void* __restrict__ o1, void* __restrict__ o2) {
  __shared__ short As[2 * BM * 32];
  __shared__ short Bs[2 * BM * 32];
  const int tid = threadIdx.x;
  const int lane = tid & 63, wid = tid >> 6;
  const int wm = wid >> 1, wn = wid & 1;
  const int l16 = lane & 15, lg = lane >> 4;
  const long r0 = (long)blockIdx.y * BM;
  const long n0 = (long)blockIdx.x * BN;

  f32x4 acc[4][4];
#pragma unroll
  for (int m = 0; m < 4; ++m)
#pragma unroll
    for (int n = 0; n < 4; ++n) {
      f32x4 z = {0.f, 0.f, 0.f, 0.f};
      acc[m][n] = z;
    }

  const int sr = lane >> 2;       // 0..15
  const int sc = (lane & 3) * 8;  // 0,8,16,24
  const short* ga0 = A + (r0 + wid * 16 + sr) * (long)K + sc;
  const short* ga1 = ga0 + 64 * (long)K;
  const short* gb0 = Bt + (n0 + wid * 16 + sr) * (long)K + sc;
  const short* gb1 = gb0 + 64 * (long)K;
  short* la0 = &As[wid * 16 * 32];
  short* la1 = la0 + 64 * 32;
  short* lb0 = &Bs[wid * 16 * 32];
  short* lb1 = lb0 + 64 * 32;

  for (int kt = 0; kt < K; kt += 64) {
    __syncthreads();
#pragma unroll
    for (int p = 0; p < 2; ++p) {
      gld16(ga0 + kt + p * 32, la0 + p * (BM * 32));
      gld16(ga1 + kt + p * 32, la1 + p * (BM * 32));
      gld16(gb0 + kt + p * 32, lb0 + p * (BM * 32));
      gld16(gb1 + kt + p * 32, lb1 + p * (BM * 32));
    }
    __syncthreads();
#pragma unroll
    for (int p = 0; p < 2; ++p) {
      short8 af[4], bfr[4];
#pragma unroll
      for (int m = 0; m < 4; ++m)
        af[m] = *(const short8*)&As[p * (BM * 32) + (wm * 64 + m * 16 + l16) * 32 + lg * 8];
#pragma unroll
      for (int n = 0; n < 4; ++n)
        bfr[n] = *(const short8*)&Bs[p * (BM * 32) + (wn * 64 + n * 16 + l16) * 32 + lg * 8];
#pragma unroll
      for (int m = 0; m < 4; ++m)
#pragma unroll
        for (int n = 0; n < 4; ++n) acc[m][n] = mfma16(af[m], bfr[n], acc[m][n]);
    }
  }

#pragma unroll
  for (int m = 0; m < 4; ++m) {
    const long rowb = r0 + wm * 64 + m * 16 + lg * 4;
#pragma unroll
    for (int n = 0; n < 4; ++n) {
      const long col = n0 + wn * 64 + n * 16 + l16;
#pragma unroll
      for (int j = 0; j < 4; ++j) {
        float val = acc[m][n][j];
        const long rr = rowb + j;
        if (MODE == 0) {
          const int c10 = (int)col & 1023;
          const int which = (int)col >> 10;
          const float* bb = which == 0 ? c0 : which == 1 ? c1 : c2;
          short* oo = (short*)(which == 0 ? o0 : which == 1 ? o1 : o2);
          val += bb[c10];
          const long bidx = rr >> 11, sidx = rr & 2047;
          const int h = c10 >> 6, hs = c10 & 63;
          oo[(((bidx * NH) + h) * SEQ + sidx) * HSZ + hs] = f2bf(val);
        } else if (MODE == 1) {
          val += c0[col] + res[rr * D_MODEL + col];
          ((float*)o0)[rr * D_MODEL + col] = val;
        } else if (MODE == 2) {
          val += c0[col];
          const float g = 0.5f * val * (1.0f + erff(val * 0.70710678118654752f));
          ((short*)o0)[rr * DFF_ + col] = f2bf(g);
        } else {
          val += c0[col] + res[rr * D_MODEL + col];
          ((float*)o0)[rr * D_MODEL + col] = val;
        }
      }
    }
  }
}

// ---------------- flash attention: swapped QK^T, O^T accumulation ----------------
// grid (S/128, B*H); block 256 = 4 waves; wave owns 32 q rows; KV tile 64.
// K/V tiles: linear [64][64] shorts with XOR granule swizzle g' = g ^ (row&7).
__global__ void attn_kernel(const short* __restrict__ q, const short* __restrict__ k,
                            const short* __restrict__ vt, short* __restrict__ att) {
  const int qt = (int)gridDim.x - 1 - (int)blockIdx.x;  // heavy blocks first
  const int bh = blockIdx.y;
  const int b = bh >> 4, h = bh & 15;
  const int tid = threadIdx.x;
  const int lane = tid & 63, wq = tid >> 6;
  const int l16 = lane & 15, lg = lane >> 4;
  const long base = (long)bh * SEQ * HSZ;

  __shared__ short Ks[64 * 64];    // [t][d] swizzled
  __shared__ short Vts[64 * 64];   // [hs][t] swizzled
  __shared__ short Ps[4 * 32 * 72];
  short* Psw = &Ps[wq * 32 * 72];

  const int R0 = qt * 128 + wq * 32;

  // Q fragments: lane l16 = q row (within 16-tile), d contiguous
  short8 qf[2][2];
#pragma unroll
  for (int qn = 0; qn < 2; ++qn)
#pragma unroll
    for (int kk = 0; kk < 2; ++kk)
      qf[qn][kk] =
          *(const short8*)(q + base + (long)(R0 + qn * 16 + l16) * HSZ + kk * 32 + lg * 8);

  float m_[2] = {-INFINITY, -INFINITY};
  float l_[2] = {0.f, 0.f};
  f32x4 oacc[2][4];
#pragma unroll
  for (int qn = 0; qn < 2; ++qn)
#pragma unroll
    for (int hf = 0; hf < 4; ++hf) {
      f32x4 z = {0.f, 0.f, 0.f, 0.f};
      oacc[qn][hf] = z;
    }

  const int srow = tid >> 3;            // 0..31
  const int wg = tid & 7;               // write granule
  const int swc = (wg ^ (srow & 7)) * 8;  // swizzled write col (shorts)
  // swizzled read cols per kk (shorts)
  const int rc0 = ((0 * 4 + lg) ^ (l16 & 7)) * 8;
  const int rc1 = ((1 * 4 + lg) ^ (l16 & 7)) * 8;
  const int tend = (qt + 1) * 128;

  // T14 prologue: issue tile-0 loads
  short8 kst[2], vst[2];
#pragma unroll
  for (int it = 0; it < 2; ++it) {
    const int r = srow + it * 32;
    kst[it] = *(const short8*)(k + base + (long)r * HSZ + wg * 8);
    vst[it] = *(const short8*)(vt + base + (long)r * SEQ + wg * 8);
  }

  for (int t0 = 0; t0 < tend; t0 += 64) {
    // write staged regs -> LDS (swizzled)
#pragma unroll
    for (int it = 0; it < 2; ++it) {
      const int r = srow + it * 32;
      *(short8*)&Ks[r * 64 + swc] = kst[it];
      *(short8*)&Vts[r * 64 + swc] = vst[it];
    }
    __syncthreads();
    // issue next-tile loads early (latency hides under compute below)
    if (t0 + 64 < tend) {
#pragma unroll
      for (int it = 0; it < 2; ++it) {
        const int r = srow + it * 32;
        kst[it] = *(const short8*)(k + base + (long)(t0 + 64 + r) * HSZ + wg * 8);
        vst[it] = *(const short8*)(vt + base + (long)r * SEQ + t0 + 64 + wg * 8);
      }
    }

    if (t0 <= R0 + 31) {
      // S^T = K Q^T : sf[tt][qn], lane holds t = t0+tt*16+lg*4+j for q row qn*16+l16
      f32x4 sf[4][2];
#pragma unroll
      for (int tt = 0; tt < 4; ++tt)
#pragma unroll
        for (int qn = 0; qn < 2; ++qn) {
          f32x4 z = {0.f, 0.f, 0.f, 0.f};
          sf[tt][qn] = z;
        }
      __builtin_amdgcn_s_setprio(1);
#pragma unroll
      for (int kk = 0; kk < 2; ++kk)
#pragma unroll
        for (int tt = 0; tt < 4; ++tt) {
          short8 kf =
              *(const short8*)&Ks[(tt * 16 + l16) * 64 + (kk ? rc1 : rc0) + kk * 0];
#pragma unroll
          for (int qn = 0; qn < 2; ++qn) sf[tt][qn] = mfma16(kf, qf[qn][kk], sf[tt][qn]);
        }
      __builtin_amdgcn_s_setprio(0);

      const bool domask = (t0 + 63 > R0);
      const int tb = t0 + lg * 4;
#pragma unroll
      for (int tt = 0; tt < 4; ++tt)
#pragma unroll
        for (int qn = 0; qn < 2; ++qn) {
          const int qg = R0 + qn * 16 + l16;
#pragma unroll
          for (int j = 0; j < 4; ++j) {
            float s = sf[tt][qn][j] * 0.125f;
            if (domask && (tb + tt * 16 + j > qg)) s = -INFINITY;
            sf[tt][qn][j] = s;
          }
        }

      // online softmax, state lane-local (lane l16 owns its q rows)
#pragma unroll
      for (int qn = 0; qn < 2; ++qn) {
        float mx = sf[0][qn][0];
#pragma unroll
        for (int tt = 0; tt < 4; ++tt)
#pragma unroll
          for (int j = 0; j < 4; ++j) mx = fmaxf(mx, sf[tt][qn][j]);
        mx = fmaxf(mx, __shfl_xor(mx, 16, 64));
        mx = fmaxf(mx, __shfl_xor(mx, 32, 64));
        const float mnew = fmaxf(m_[qn], mx);
        const float rc = __expf(m_[qn] - mnew);
        float sum = 0.f;
#pragma unroll
        for (int tt = 0; tt < 4; ++tt)
#pragma unroll
          for (int j = 0; j < 4; ++j) {
            const float p = __expf(sf[tt][qn][j] - mnew);
            sf[tt][qn][j] = p;
            sum += p;
          }
        sum += __shfl_xor(sum, 16, 64);
        sum += __shfl_xor(sum, 32, 64);
        l_[qn] = l_[qn] * rc + sum;
        m_[qn] = mnew;
#pragma unroll
        for (int hf = 0; hf < 4; ++hf)
#pragma unroll
          for (int j = 0; j < 4; ++j) oacc[qn][hf][j] *= rc;
      }

      // P -> per-wave LDS (packed u32 writes)
#pragma unroll
      for (int qn = 0; qn < 2; ++qn)
#pragma unroll
        for (int tt = 0; tt < 4; ++tt) {
          const int ro = (qn * 16 + l16) * 72 + tt * 16 + lg * 4;
          *(unsigned*)&Psw[ro] = packbf2(sf[tt][qn][0], sf[tt][qn][1]);
          *(unsigned*)&Psw[ro + 2] = packbf2(sf[tt][qn][2], sf[tt][qn][3]);
        }

      // O^T += V^T P^T
      __builtin_amdgcn_s_setprio(1);
#pragma unroll
      for (int kk = 0; kk < 2; ++kk) {
        short8 pa[2];
#pragma unroll
        for (int qn = 0; qn < 2; ++qn)
          pa[qn] = *(const short8*)&Psw[(qn * 16 + l16) * 72 + kk * 32 + lg * 8];
#pragma unroll
        for (int hf = 0; hf < 4; ++hf) {
          short8 vf = *(const short8*)&Vts[(hf * 16 + l16) * 64 + (kk ? rc1 : rc0)];
#pragma unroll
          for (int qn = 0; qn < 2; ++qn)
            oacc[qn][hf] = mfma16(vf, pa[qn], oacc[qn][hf]);
        }
      }
      __builtin_amdgcn_s_setprio(0);
    }
    __syncthreads();
  }

  // epilogue: lane holds O^T[hs = hf*16+lg*4+j][q = R0+qn*16+l16]
#pragma unroll
  for (int qn = 0; qn < 2; ++qn) {
    const float inv = 1.0f / l_[qn];
    const long row = R0 + qn * 16 + l16;
#pragma unroll
    for (int hf = 0; hf < 4; ++hf) {
      short4v o4;
#pragma unroll
      for (int j = 0; j < 4; ++j) o4[j] = f2bf(oacc[qn][hf][j] * inv);
      *(short4v*)(att + ((long)b * SEQ + row) * D_MODEL + h * HSZ + hf * 16 + lg * 4) = o4;
    }
  }
}

// ---------------- launch ----------------
extern "C" void kernel_launch(void* const* d_in, const int* in_sizes, int n_in,
                              void* d_out, int out_size, void* d_ws, size_t ws_size,
                              hipStream_t stream) {
  const float* x = (const float*)d_in[0];
  const float* Wq = (const float*)d_in[1];
  const float* bq = (const float*)d_in[2];
  const float* Wk = (const float*)d_in[3];
  const float* bk = (const float*)d_in[4];
  const float* Wv = (const float*)d_in[5];
  const float* bv = (const float*)d_in[6];
  const float* Wp = (const float*)d_in[7];
  const float* bp = (const float*)d_in[8];
  const float* g1 = (const float*)d_in[9];
  const float* be1 = (const float*)d_in[10];
  const float* g2 = (const float*)d_in[11];
  const float* be2 = (const float*)d_in[12];
  const float* W1 = (const float*)d_in[13];
  const float* b1 = (const float*)d_in[14];
  const float* W2 = (const float*)d_in[15];
  const float* b2 = (const float*)d_in[16];
  float* out = (float*)d_out;
  char* ws = (char*)d_ws;

  if (ws_size < 209715200ull) return;

  short* WqkvT = (short*)(ws + 0);          // [3072][1024] bf16
  short* WpT = (short*)(ws + 6291456);      // [1024][1024]
  short* W1T = (short*)(ws + 8388608);      // [4096][1024]
  short* W2T = (short*)(ws + 16777216);     // [1024][4096]
  short* xn = (short*)(ws + 25165824);      // [8192][1024] (ln out; vt aliases after qkv)
  short* vt = (short*)(ws + 25165824);      // [B,H,HS,S] (aliases xn)
  short* qb = (short*)(ws + 41943040);      // [B,H,S,HS]
  short* kb = (short*)(ws + 58720256);
  short* vb = (short*)(ws + 75497472);
  short* att = (short*)(ws + 92274688);     // [8192][1024]
  float* x1 = (float*)(ws + 109051904);     // [8192][1024] f32
  short* hb = (short*)(ws + 142606336);     // [8192][4096]

  dim3 tb(32, 8);
  transpose_qkv_kernel<<<dim3(2, 32, 48), tb, 0, stream>>>(Wq, Wk, Wv, WqkvT);
  transpose_gen_kernel<<<dim3(32, 32), tb, 0, stream>>>(Wp, WpT, 1024, 1024);
  transpose_gen_kernel<<<dim3(128, 32), tb, 0, stream>>>(W1, W1T, 1024, 4096);
  transpose_gen_kernel<<<dim3(32, 128), tb, 0, stream>>>(W2, W2T, 4096, 1024);
  ln_kernel<<<8192, 256, 0, stream>>>(x, g1, be1, xn);
  gemm_kernel<0><<<dim3(24, 64), 256, 0, stream>>>(xn, WqkvT, 1024, bq, bk, bv, nullptr,
                                                   qb, kb, vb);
  v_transpose_kernel<<<dim3(32, 64), 256, 0, stream>>>(vb, vt);
  attn_kernel<<<dim3(16, 64), 256, 0, stream>>>(qb, kb, vt, att);
  gemm_kernel<1><<<dim3(8, 64), 256, 0, stream>>>(att, WpT, 1024, bp, nullptr, nullptr, x,
                                                  x1, nullptr, nullptr);
  ln_kernel<<<8192, 256, 0, stream>>>(x1, g2, be2, xn);
  gemm_kernel<2><<<dim3(32, 64), 256, 0, stream>>>(xn, W1T, 1024, b1, nullptr, nullptr,
                                                   nullptr, hb, nullptr, nullptr);
  gemm_kernel<3><<<dim3(8, 64), 256, 0, stream>>>(hb, W2T, 4096, b2, nullptr, nullptr, x1,
                                                  out, nullptr, nullptr);
}

// Round 4
// 462.961 us; speedup vs baseline: 1.1659x; 1.1659x over previous
//
#include <hip/hip_runtime.h>
#include <hip/hip_bf16.h>

#define D_MODEL 1024
#define SEQ 2048
#define NH 16
#define HSZ 64
#define DFF_ 4096

typedef __attribute__((ext_vector_type(8))) short short8;
typedef __attribute__((ext_vector_type(4))) short short4v;
typedef __attribute__((ext_vector_type(4))) float f32x4;

static __device__ __forceinline__ short f2bf(float f) {
  unsigned u = __builtin_bit_cast(unsigned, f);
  u = u + 0x7fffu + ((u >> 16) & 1u);
  return (short)(u >> 16);
}

static __device__ __forceinline__ unsigned packbf2(float a, float b) {
  return (unsigned)(unsigned short)f2bf(a) | ((unsigned)(unsigned short)f2bf(b) << 16);
}

static __device__ __forceinline__ f32x4 mfma16(short8 a, short8 b, f32x4 c) {
  return __builtin_amdgcn_mfma_f32_16x16x32_bf16(a, b, c, 0, 0, 0);
}

static __device__ __forceinline__ void gld16(const short* g, short* l) {
  __builtin_amdgcn_global_load_lds((const __attribute__((address_space(1))) void*)g,
                                   (__attribute__((address_space(3))) void*)l, 16, 0, 0);
}

// ---------------- weight transpose/convert kernels ----------------
__global__ void transpose_qkv_kernel(const float* __restrict__ Wq, const float* __restrict__ Wk,
                                     const float* __restrict__ Wv, short* __restrict__ dst) {
  __shared__ float tile[32][33];
  const int z = blockIdx.z;
  const int which = z >> 4, hh = z & 15;
  const float* src = (which == 0 ? Wq : which == 1 ? Wk : Wv) + (long)hh * (D_MODEL * HSZ);
  const int c0 = blockIdx.x * 32, r0 = blockIdx.y * 32;
  const int tx = threadIdx.x, ty = threadIdx.y;
#pragma unroll
  for (int i = 0; i < 4; ++i)
    tile[ty + 8 * i][tx] = src[(long)(r0 + ty + 8 * i) * HSZ + c0 + tx];
  __syncthreads();
#pragma unroll
  for (int i = 0; i < 4; ++i)
    dst[((long)which * 1024 + hh * 64 + c0 + ty + 8 * i) * D_MODEL + r0 + tx] =
        f2bf(tile[tx][ty + 8 * i]);
}

__global__ void transpose_gen_kernel(const float* __restrict__ src, short* __restrict__ dst,
                                     int R, int C) {
  __shared__ float tile[32][33];
  const int c0 = blockIdx.x * 32, r0 = blockIdx.y * 32;
  const int tx = threadIdx.x, ty = threadIdx.y;
#pragma unroll
  for (int i = 0; i < 4; ++i)
    tile[ty + 8 * i][tx] = src[(long)(r0 + ty + 8 * i) * C + c0 + tx];
  __syncthreads();
#pragma unroll
  for (int i = 0; i < 4; ++i)
    dst[(long)(c0 + ty + 8 * i) * R + r0 + tx] = f2bf(tile[tx][ty + 8 * i]);
}

// V: [B,H,S,HS] -> [B,H,HS,S] (bf16)
__global__ void v_transpose_kernel(const short* __restrict__ vb, short* __restrict__ vt) {
  __shared__ short tile[64 * 72];
  const int bh = blockIdx.y;
  const int t0 = blockIdx.x * 64;
  const long base = (long)bh * SEQ * HSZ;
  const int tid = threadIdx.x;
  const int r = tid >> 3, c = (tid & 7) * 8;
#pragma unroll
  for (int it = 0; it < 2; ++it) {
    const int rr = r + it * 32;
    *(short8*)&tile[rr * 72 + c] = *(const short8*)(vb + base + (long)(t0 + rr) * HSZ + c);
  }
  __syncthreads();
#pragma unroll
  for (int it = 0; it < 2; ++it) {
    const int rr = r + it * 32;  // hs row
    short8 o;
#pragma unroll
    for (int u = 0; u < 8; ++u) o[u] = tile[(c + u) * 72 + rr];
    *(short8*)(vt + base + (long)rr * SEQ + t0 + c) = o;
  }
}

// ---------------- layernorm (f32 in -> bf16 out) ----------------
__global__ void ln_kernel(const float* __restrict__ x, const float* __restrict__ w,
                          const float* __restrict__ b, short* __restrict__ out) {
  const int row = blockIdx.x;
  const float* xr = x + (size_t)row * D_MODEL;
  const int t = threadIdx.x;  // 256
  float4 v = *(const float4*)(xr + t * 4);
  float s = v.x + v.y + v.z + v.w;
  float s2 = v.x * v.x + v.y * v.y + v.z * v.z + v.w * v.w;
#pragma unroll
  for (int o = 1; o < 64; o <<= 1) {
    s += __shfl_xor(s, o, 64);
    s2 += __shfl_xor(s2, o, 64);
  }
  __shared__ float ps[8];
  const int lane = t & 63, wid = t >> 6;
  if (lane == 0) { ps[wid] = s; ps[wid + 4] = s2; }
  __syncthreads();
  s = ps[0] + ps[1] + ps[2] + ps[3];
  s2 = ps[4] + ps[5] + ps[6] + ps[7];
  const float mu = s * (1.0f / D_MODEL);
  const float var = s2 * (1.0f / D_MODEL) - mu * mu;
  const float rs = rsqrtf(var + 1e-5f);
  float4 wv = *(const float4*)(w + t * 4);
  float4 bv = *(const float4*)(b + t * 4);
  short4v o4;
  o4[0] = f2bf((v.x - mu) * rs * wv.x + bv.x);
  o4[1] = f2bf((v.y - mu) * rs * wv.y + bv.y);
  o4[2] = f2bf((v.z - mu) * rs * wv.z + bv.z);
  o4[3] = f2bf((v.w - mu) * rs * wv.w + bv.w);
  *(short4v*)(out + (size_t)row * D_MODEL + t * 4) = o4;
}

// ---------------- GEMM (m97 structure, BK=64 as two 32-K panels) ----------------
// MODE 0: qkv  MODE 1: proj(+res)  MODE 2: ffn1(+gelu)  MODE 3: ffn2(+res)
#define BM 128
#define BN 128

template <int MODE>
__global__ void gemm_kernel(const short* __restrict__ A, const short* __restrict__ Bt,
                            const int K, const float* __restrict__ c0,
                            const float* __restrict__ c1, const float* __restrict__ c2,
                            const float* __restrict__ res, void* __restrict__ o0,
                            void* __restrict__ o1, void* __restrict__ o2) {
  __shared__ short As[2 * BM * 32];
  __shared__ short Bs[2 * BM * 32];
  const int tid = threadIdx.x;
  const int lane = tid & 63, wid = tid >> 6;
  const int wm = wid >> 1, wn = wid & 1;
  const int l16 = lane & 15, lg = lane >> 4;
  const long r0 = (long)blockIdx.y * BM;
  const long n0 = (long)blockIdx.x * BN;

  f32x4 acc[4][4];
#pragma unroll
  for (int m = 0; m < 4; ++m)
#pragma unroll
    for (int n = 0; n < 4; ++n) {
      f32x4 z = {0.f, 0.f, 0.f, 0.f};
      acc[m][n] = z;
    }

  const int sr = lane >> 2;       // 0..15
  const int sc = (lane & 3) * 8;  // 0,8,16,24
  const short* ga0 = A + (r0 + wid * 16 + sr) * (long)K + sc;
  const short* ga1 = ga0 + 64 * (long)K;
  const short* gb0 = Bt + (n0 + wid * 16 + sr) * (long)K + sc;
  const short* gb1 = gb0 + 64 * (long)K;
  short* la0 = &As[wid * 16 * 32];
  short* la1 = la0 + 64 * 32;
  short* lb0 = &Bs[wid * 16 * 32];
  short* lb1 = lb0 + 64 * 32;

  for (int kt = 0; kt < K; kt += 64) {
    __syncthreads();
#pragma unroll
    for (int p = 0; p < 2; ++p) {
      gld16(ga0 + kt + p * 32, la0 + p * (BM * 32));
      gld16(ga1 + kt + p * 32, la1 + p * (BM * 32));
      gld16(gb0 + kt + p * 32, lb0 + p * (BM * 32));
      gld16(gb1 + kt + p * 32, lb1 + p * (BM * 32));
    }
    __syncthreads();
#pragma unroll
    for (int p = 0; p < 2; ++p) {
      short8 af[4], bfr[4];
#pragma unroll
      for (int m = 0; m < 4; ++m)
        af[m] = *(const short8*)&As[p * (BM * 32) + (wm * 64 + m * 16 + l16) * 32 + lg * 8];
#pragma unroll
      for (int n = 0; n < 4; ++n)
        bfr[n] = *(const short8*)&Bs[p * (BM * 32) + (wn * 64 + n * 16 + l16) * 32 + lg * 8];
#pragma unroll
      for (int m = 0; m < 4; ++m)
#pragma unroll
        for (int n = 0; n < 4; ++n) acc[m][n] = mfma16(af[m], bfr[n], acc[m][n]);
    }
  }

#pragma unroll
  for (int m = 0; m < 4; ++m) {
    const long rowb = r0 + wm * 64 + m * 16 + lg * 4;
#pragma unroll
    for (int n = 0; n < 4; ++n) {
      const long col = n0 + wn * 64 + n * 16 + l16;
#pragma unroll
      for (int j = 0; j < 4; ++j) {
        float val = acc[m][n][j];
        const long rr = rowb + j;
        if (MODE == 0) {
          const int c10 = (int)col & 1023;
          const int which = (int)col >> 10;
          const float* bb = which == 0 ? c0 : which == 1 ? c1 : c2;
          short* oo = (short*)(which == 0 ? o0 : which == 1 ? o1 : o2);
          val += bb[c10];
          const long bidx = rr >> 11, sidx = rr & 2047;
          const int h = c10 >> 6, hs = c10 & 63;
          oo[(((bidx * NH) + h) * SEQ + sidx) * HSZ + hs] = f2bf(val);
        } else if (MODE == 1) {
          val += c0[col] + res[rr * D_MODEL + col];
          ((float*)o0)[rr * D_MODEL + col] = val;
        } else if (MODE == 2) {
          val += c0[col];
          const float g = 0.5f * val * (1.0f + erff(val * 0.70710678118654752f));
          ((short*)o0)[rr * DFF_ + col] = f2bf(g);
        } else {
          val += c0[col] + res[rr * D_MODEL + col];
          ((float*)o0)[rr * D_MODEL + col] = val;
        }
      }
    }
  }
}

// ---------------- flash attention: swapped QK^T, O^T accumulation ----------------
// grid (B*H, S/128); block 256 = 4 waves; wave owns 32 q rows; KV tile 64.
// LPT: qt = NT-1-blockIdx.y so heaviest blocks dispatch first.
// Softmax in log2 domain (exp2), defer-max (THR=8), per-lane deferred l-sum.
#define SM_SCALE 0.18033688011112042f  /* 0.125 * log2(e) */

__global__ void attn_kernel(const short* __restrict__ q, const short* __restrict__ k,
                            const short* __restrict__ vt, short* __restrict__ att) {
  const int qt = (SEQ / 128 - 1) - (int)blockIdx.y;  // heavy blocks first
  const int bh = blockIdx.x;
  const int b = bh >> 4, h = bh & 15;
  const int tid = threadIdx.x;
  const int lane = tid & 63, wq = tid >> 6;
  const int l16 = lane & 15, lg = lane >> 4;
  const long base = (long)bh * SEQ * HSZ;

  __shared__ short Ks[64 * 72];    // [t][d] padded
  __shared__ short Vts[64 * 72];   // [hs][t] padded
  __shared__ short Ps[4 * 32 * 72];
  short* Psw = &Ps[wq * 32 * 72];

  const int R0 = qt * 128 + wq * 32;

  // Q fragments: lane l16 = q row (within 16-tile), d contiguous
  short8 qf[2][2];
#pragma unroll
  for (int qn = 0; qn < 2; ++qn)
#pragma unroll
    for (int kk = 0; kk < 2; ++kk)
      qf[qn][kk] =
          *(const short8*)(q + base + (long)(R0 + qn * 16 + l16) * HSZ + kk * 32 + lg * 8);

  float m_[2] = {-INFINITY, -INFINITY};
  float l_[2] = {0.f, 0.f};
  f32x4 oacc[2][4];
#pragma unroll
  for (int qn = 0; qn < 2; ++qn)
#pragma unroll
    for (int hf = 0; hf < 4; ++hf) {
      f32x4 z = {0.f, 0.f, 0.f, 0.f};
      oacc[qn][hf] = z;
    }

  const int srow = tid >> 3, scol = (tid & 7) * 8;
  const int tend = (qt + 1) * 128;

  for (int t0 = 0; t0 < tend; t0 += 64) {
    __syncthreads();
#pragma unroll
    for (int it = 0; it < 2; ++it) {
      const int r = srow + it * 32;
      *(short8*)&Ks[r * 72 + scol] =
          *(const short8*)(k + base + (long)(t0 + r) * HSZ + scol);
      *(short8*)&Vts[r * 72 + scol] =
          *(const short8*)(vt + base + (long)r * SEQ + t0 + scol);
    }
    __syncthreads();

    if (t0 <= R0 + 31) {
      // S^T = K Q^T : sf[tt][qn], lane holds t = t0+tt*16+lg*4+j for q row qn*16+l16
      f32x4 sf[4][2];
#pragma unroll
      for (int tt = 0; tt < 4; ++tt)
#pragma unroll
        for (int qn = 0; qn < 2; ++qn) {
          f32x4 z = {0.f, 0.f, 0.f, 0.f};
          sf[tt][qn] = z;
        }
      __builtin_amdgcn_s_setprio(1);
#pragma unroll
      for (int kk = 0; kk < 2; ++kk)
#pragma unroll
        for (int tt = 0; tt < 4; ++tt) {
          short8 kf = *(const short8*)&Ks[(tt * 16 + l16) * 72 + kk * 32 + lg * 8];
#pragma unroll
          for (int qn = 0; qn < 2; ++qn) sf[tt][qn] = mfma16(kf, qf[qn][kk], sf[tt][qn]);
        }
      __builtin_amdgcn_s_setprio(0);

      const bool domask = (t0 + 63 > R0);
      const int tb = t0 + lg * 4;
#pragma unroll
      for (int tt = 0; tt < 4; ++tt)
#pragma unroll
        for (int qn = 0; qn < 2; ++qn) {
          const int qg = R0 + qn * 16 + l16;
#pragma unroll
          for (int j = 0; j < 4; ++j) {
            float s = sf[tt][qn][j] * SM_SCALE;
            if (domask && (tb + tt * 16 + j > qg)) s = -INFINITY;
            sf[tt][qn][j] = s;
          }
        }

      // row max (2 shfl per qn), defer-max rescale skip
      float mx[2];
#pragma unroll
      for (int qn = 0; qn < 2; ++qn) {
        float m0 = sf[0][qn][0];
#pragma unroll
        for (int tt = 0; tt < 4; ++tt)
#pragma unroll
          for (int j = 0; j < 4; ++j) m0 = fmaxf(m0, sf[tt][qn][j]);
        m0 = fmaxf(m0, __shfl_xor(m0, 16, 64));
        m0 = fmaxf(m0, __shfl_xor(m0, 32, 64));
        mx[qn] = m0;
      }
      const int ok = (mx[0] <= m_[0] + 8.f) && (mx[1] <= m_[1] + 8.f);
      if (!__all(ok)) {
#pragma unroll
        for (int qn = 0; qn < 2; ++qn) {
          const float mnew = fmaxf(m_[qn], mx[qn]);
          const float rc = exp2f(m_[qn] - mnew);
          m_[qn] = mnew;
          l_[qn] *= rc;
#pragma unroll
          for (int hf = 0; hf < 4; ++hf)
#pragma unroll
            for (int j = 0; j < 4; ++j) oacc[qn][hf][j] *= rc;
        }
      }
#pragma unroll
      for (int qn = 0; qn < 2; ++qn) {
        float sum = 0.f;
#pragma unroll
        for (int tt = 0; tt < 4; ++tt)
#pragma unroll
          for (int j = 0; j < 4; ++j) {
            const float p = exp2f(sf[tt][qn][j] - m_[qn]);
            sf[tt][qn][j] = p;
            sum += p;
          }
        l_[qn] += sum;  // per-lane partial; reduced in epilogue
      }

      // P -> per-wave LDS (packed u32 writes)
#pragma unroll
      for (int qn = 0; qn < 2; ++qn)
#pragma unroll
        for (int tt = 0; tt < 4; ++tt) {
          const int ro = (qn * 16 + l16) * 72 + tt * 16 + lg * 4;
          *(unsigned*)&Psw[ro] = packbf2(sf[tt][qn][0], sf[tt][qn][1]);
          *(unsigned*)&Psw[ro + 2] = packbf2(sf[tt][qn][2], sf[tt][qn][3]);
        }

      // O^T += V^T P^T
      __builtin_amdgcn_s_setprio(1);
#pragma unroll
      for (int kk = 0; kk < 2; ++kk) {
        short8 pa[2];
#pragma unroll
        for (int qn = 0; qn < 2; ++qn)
          pa[qn] = *(const short8*)&Psw[(qn * 16 + l16) * 72 + kk * 32 + lg * 8];
#pragma unroll
        for (int hf = 0; hf < 4; ++hf) {
          short8 vf = *(const short8*)&Vts[(hf * 16 + l16) * 72 + kk * 32 + lg * 8];
#pragma unroll
          for (int qn = 0; qn < 2; ++qn)
            oacc[qn][hf] = mfma16(vf, pa[qn], oacc[qn][hf]);
        }
      }
      __builtin_amdgcn_s_setprio(0);
    }
  }

  // epilogue: reduce l across lg groups; lane holds O^T[hs=hf*16+lg*4+j][q=R0+qn*16+l16]
#pragma unroll
  for (int qn = 0; qn < 2; ++qn) {
    float lt = l_[qn];
    lt += __shfl_xor(lt, 16, 64);
    lt += __shfl_xor(lt, 32, 64);
    const float inv = 1.0f / lt;
    const long row = R0 + qn * 16 + l16;
#pragma unroll
    for (int hf = 0; hf < 4; ++hf) {
      short4v o4;
#pragma unroll
      for (int j = 0; j < 4; ++j) o4[j] = f2bf(oacc[qn][hf][j] * inv);
      *(short4v*)(att + ((long)b * SEQ + row) * D_MODEL + h * HSZ + hf * 16 + lg * 4) = o4;
    }
  }
}

// ---------------- launch ----------------
extern "C" void kernel_launch(void* const* d_in, const int* in_sizes, int n_in,
                              void* d_out, int out_size, void* d_ws, size_t ws_size,
                              hipStream_t stream) {
  const float* x = (const float*)d_in[0];
  const float* Wq = (const float*)d_in[1];
  const float* bq = (const float*)d_in[2];
  const float* Wk = (const float*)d_in[3];
  const float* bk = (const float*)d_in[4];
  const float* Wv = (const float*)d_in[5];
  const float* bv = (const float*)d_in[6];
  const float* Wp = (const float*)d_in[7];
  const float* bp = (const float*)d_in[8];
  const float* g1 = (const float*)d_in[9];
  const float* be1 = (const float*)d_in[10];
  const float* g2 = (const float*)d_in[11];
  const float* be2 = (const float*)d_in[12];
  const float* W1 = (const float*)d_in[13];
  const float* b1 = (const float*)d_in[14];
  const float* W2 = (const float*)d_in[15];
  const float* b2 = (const float*)d_in[16];
  float* out = (float*)d_out;
  char* ws = (char*)d_ws;

  if (ws_size < 209715200ull) return;

  short* WqkvT = (short*)(ws + 0);          // [3072][1024] bf16
  short* WpT = (short*)(ws + 6291456);      // [1024][1024]
  short* W1T = (short*)(ws + 8388608);      // [4096][1024]
  short* W2T = (short*)(ws + 16777216);     // [1024][4096]
  short* xn = (short*)(ws + 25165824);      // [8192][1024] (ln out; vt aliases after qkv)
  short* vt = (short*)(ws + 25165824);      // [B,H,HS,S] (aliases xn)
  short* qb = (short*)(ws + 41943040);      // [B,H,S,HS]
  short* kb = (short*)(ws + 58720256);
  short* vb = (short*)(ws + 75497472);
  short* att = (short*)(ws + 92274688);     // [8192][1024]
  float* x1 = (float*)(ws + 109051904);     // [8192][1024] f32
  short* hb = (short*)(ws + 142606336);     // [8192][4096]

  dim3 tb(32, 8);
  transpose_qkv_kernel<<<dim3(2, 32, 48), tb, 0, stream>>>(Wq, Wk, Wv, WqkvT);
  transpose_gen_kernel<<<dim3(32, 32), tb, 0, stream>>>(Wp, WpT, 1024, 1024);
  transpose_gen_kernel<<<dim3(128, 32), tb, 0, stream>>>(W1, W1T, 1024, 4096);
  transpose_gen_kernel<<<dim3(32, 128), tb, 0, stream>>>(W2, W2T, 4096, 1024);
  ln_kernel<<<8192, 256, 0, stream>>>(x, g1, be1, xn);
  gemm_kernel<0><<<dim3(24, 64), 256, 0, stream>>>(xn, WqkvT, 1024, bq, bk, bv, nullptr,
                                                   qb, kb, vb);
  v_transpose_kernel<<<dim3(32, 64), 256, 0, stream>>>(vb, vt);
  attn_kernel<<<dim3(64, 16), 256, 0, stream>>>(qb, kb, vt, att);
  gemm_kernel<1><<<dim3(8, 64), 256, 0, stream>>>(att, WpT, 1024, bp, nullptr, nullptr, x,
                                                  x1, nullptr, nullptr);
  ln_kernel<<<8192, 256, 0, stream>>>(x1, g2, be2, xn);
  gemm_kernel<2><<<dim3(32, 64), 256, 0, stream>>>(xn, W1T, 1024, b1, nullptr, nullptr,
                                                   nullptr, hb, nullptr, nullptr);
  gemm_kernel<3><<<dim3(8, 64), 256, 0, stream>>>(hb, W2T, 4096, b2, nullptr, nullptr, x1,
                                                  out, nullptr, nullptr);
}